// Round 15
// baseline (102.763 us; speedup 1.0000x reference)
//
#include <hip/hip_runtime.h>
#include <math.h>

// Problem constants: FX=FY=48, CX=48, CY=36, H=72, W=96, sigma2=1
#define NPIX 6912
#define LOG2E 1.4426950408889634f

typedef __fp16 v8h  __attribute__((ext_vector_type(8)));
typedef float  v16f __attribute__((ext_vector_type(16)));

// ws byte offsets (32B-aligned). All f16 arrays [N][16] (32 B per pixel).
// A-side (rows, pixel m):
//   rowfeat: k0..15 = f1n features (16)
//   rowgeo : k0..2=ph, k3..5=ph, k6..8=pl, k9=1, k10=1, k11=w_h, k12=w_l, k13..15=0
//            (p~ = log2e*p1 hi/lo split; w = -log2e*|p1|^2/2 hi/lo split)
// B-side (cols, pixel n):
//   colfeat: k0..15 = f2n features
//   colB1  : k0..2=th, k3..5=tl, k6..8=th, k9=cA_h, k10=cA_l, k11=1, k12=1, rest 0
//   colB2  : k0..2=qh, k3..5=ql, k6..8=qh, k9=cB_h, k10=cB_l, k11=1, k12=1, rest 0
// MFMA(ageo,colB1) = p~.t + cA + w = a1;  MFMA(ageo,colB2) = p~.q + cB + w = a2
// loss slot: (2^a1 - 2^a2) * dot.  Validated R13 (absmax 7.2e-7).
#define OFF_ROWFEAT 0
#define OFF_ROWGEO  221184
#define OFF_COLFEAT 442368
#define OFF_COLB1   663552
#define OFF_COLB2   884736
#define OFF_PART    1105920   // [1296] f32 pair partials
#define OFF_NPART   1111104   // [108]  f32 preproc norm partials
#define OFF_CNT     1111552   // [1] u32 block-completion counter (zeroed by preproc)
#define NPART_BLOCKS 1296     // 24 x 54
#define NNORM_BLOCKS 108

__device__ __forceinline__ float fast_exp2(float x) { return __builtin_amdgcn_exp2f(x); }

__device__ __forceinline__ float wave_reduce_64(float v) {
    #pragma unroll
    for (int o = 32; o > 0; o >>= 1) v += __shfl_down(v, o, 64);
    return v;
}

__device__ __forceinline__ float block_reduce_256(float v, float* smem4) {
    __syncthreads();   // protect smem4 across consecutive reductions
    v = wave_reduce_64(v);
    const int lane = threadIdx.x & 63;
    const int w = threadIdx.x >> 6;
    if (lane == 0) smem4[w] = v;
    __syncthreads();
    float r = 0.0f;
    if (threadIdx.x == 0) r = smem4[0] + smem4[1] + smem4[2] + smem4[3];
    return r;
}

__device__ __forceinline__ void split_hl(float x, __fp16& h, __fp16& l) {
    h = (__fp16)x;
    l = (__fp16)(x - (float)h);
}

// 108 blocks x 64 threads (one wave per block); no atomics (partial store).
// Also zeroes the pair kernel's completion counter (kernel-boundary ordering
// guarantees visibility before any pair block runs).
__global__ __launch_bounds__(64)
void preproc_kernel(const float* __restrict__ f1, const float* __restrict__ f2,
                    const float* __restrict__ d1, const float* __restrict__ d2,
                    const float* __restrict__ pose, const float* __restrict__ pnz,
                    char* __restrict__ wsb) {
    const int i = blockIdx.x * 64 + threadIdx.x;

    __fp16* rowfeat = (__fp16*)(wsb + OFF_ROWFEAT);
    __fp16* rowgeo  = (__fp16*)(wsb + OFF_ROWGEO);
    __fp16* colfeat = (__fp16*)(wsb + OFF_COLFEAT);
    __fp16* colB1   = (__fp16*)(wsb + OFF_COLB1);
    __fp16* colB2   = (__fp16*)(wsb + OFF_COLB2);
    float*  npart   = (float*)(wsb + OFF_NPART);

    if (blockIdx.x == 0 && threadIdx.x == 0)
        *(unsigned int*)(wsb + OFF_CNT) = 0u;

    float P[12];
    #pragma unroll
    for (int k = 0; k < 12; k++) P[k] = pose[k];
    float Q[12];
    #pragma unroll
    for (int r = 0; r < 3; r++) {
        #pragma unroll
        for (int c = 0; c < 4; c++) {
            float s = 0.0f;
            #pragma unroll
            for (int k = 0; k < 4; k++) s = fmaf(pose[r * 4 + k], pnz[k * 4 + c], s);
            Q[r * 4 + c] = s;
        }
    }

    const float inv48 = 1.0f / 48.0f;
    const int u = i % 96;
    const int v = i / 96;
    const float y1 = fmaf((float)u, inv48, -1.0f);
    const float y2 = fmaf((float)v, inv48, -0.75f);

    // ---- row side ----
    const float dep1 = d1[i];
    const float px = dep1, py = y1 * dep1, pz = y2 * dep1;
    const float n1 = px * px + py * py + pz * pz;
    const float wlog = -0.5f * LOG2E * n1;

    const float ptx = LOG2E * px, pty = LOG2E * py, ptz = LOG2E * pz;
    __fp16 phx, phy, phz, plx, ply, plz, wh, wl;
    split_hl(ptx, phx, plx);
    split_hl(pty, phy, ply);
    split_hl(ptz, phz, plz);
    split_hl(wlog, wh, wl);
    {
        __fp16 rg[16] = {phx, phy, phz,  phx, phy, phz,  plx, ply, plz,
                         (__fp16)1.0f, (__fp16)1.0f, wh, wl,
                         (__fp16)0, (__fp16)0, (__fp16)0};
        *(v8h*)(rowgeo + (size_t)i * 16)     = *(v8h*)(rg);
        *(v8h*)(rowgeo + (size_t)i * 16 + 8) = *(v8h*)(rg + 8);
    }

    // ---- col side ----
    const float dep2 = d2[i];
    const float a = dep2, b = y1 * dep2, g = y2 * dep2;
    const float t0 = P[0] * a + P[1] * b + P[2]  * g + P[3];
    const float t1 = P[4] * a + P[5] * b + P[6]  * g + P[7];
    const float t2 = P[8] * a + P[9] * b + P[10] * g + P[11];
    const float q0 = Q[0] * a + Q[1] * b + Q[2]  * g + Q[3];
    const float q1 = Q[4] * a + Q[5] * b + Q[6]  * g + Q[7];
    const float q2 = Q[8] * a + Q[9] * b + Q[10] * g + Q[11];
    const float nt = t0 * t0 + t1 * t1 + t2 * t2;
    const float nq = q0 * q0 + q1 * q1 + q2 * q2;
    const float cA = -0.5f * LOG2E * nt;
    const float cB = -0.5f * LOG2E * nq;

    __fp16 thx, thy, thz, tlx, tly, tlz, cAh, cAl;
    __fp16 qhx, qhy, qhz, qlx, qly, qlz, cBh, cBl;
    split_hl(t0, thx, tlx);
    split_hl(t1, thy, tly);
    split_hl(t2, thz, tlz);
    split_hl(cA, cAh, cAl);
    split_hl(q0, qhx, qlx);
    split_hl(q1, qhy, qly);
    split_hl(q2, qhz, qlz);
    split_hl(cB, cBh, cBl);
    {
        __fp16 b1a[16] = {thx, thy, thz,  tlx, tly, tlz,  thx, thy, thz,
                          cAh, cAl, (__fp16)1.0f, (__fp16)1.0f,
                          (__fp16)0, (__fp16)0, (__fp16)0};
        *(v8h*)(colB1 + (size_t)i * 16)     = *(v8h*)(b1a);
        *(v8h*)(colB1 + (size_t)i * 16 + 8) = *(v8h*)(b1a + 8);
    }
    {
        __fp16 b2a[16] = {qhx, qhy, qhz,  qlx, qly, qlz,  qhx, qhy, qhz,
                          cBh, cBl, (__fp16)1.0f, (__fp16)1.0f,
                          (__fp16)0, (__fp16)0, (__fp16)0};
        *(v8h*)(colB2 + (size_t)i * 16)     = *(v8h*)(b2a);
        *(v8h*)(colB2 + (size_t)i * 16 + 8) = *(v8h*)(b2a + 8);
    }

    // ---- features: normalize, f16 ----
    float s1 = 0.0f, s2 = 0.0f;
    float v1[16], v2[16];
    #pragma unroll
    for (int cc = 0; cc < 16; cc++) {
        v1[cc] = f1[cc * NPIX + i];
        v2[cc] = f2[cc * NPIX + i];
        s1 = fmaf(v1[cc], v1[cc], s1);
        s2 = fmaf(v2[cc], v2[cc], s2);
    }
    const float nrm1 = sqrtf(s1), nrm2 = sqrtf(s2);
    const float r1 = 1.0f / (nrm1 + 1e-8f), r2 = 1.0f / (nrm2 + 1e-8f);
    {
        __fp16 rf[16], cf[16];
        #pragma unroll
        for (int cc = 0; cc < 16; cc++) {
            rf[cc] = (__fp16)(v1[cc] * r1);
            cf[cc] = (__fp16)(v2[cc] * r2);
        }
        *(v8h*)(rowfeat + (size_t)i * 16)     = *(v8h*)(rf);
        *(v8h*)(rowfeat + (size_t)i * 16 + 8) = *(v8h*)(rf + 8);
        *(v8h*)(colfeat + (size_t)i * 16)     = *(v8h*)(cf);
        *(v8h*)(colfeat + (size_t)i * 16 + 8) = *(v8h*)(cf + 8);
    }

    float tot = wave_reduce_64(nrm1 + nrm2);
    if (threadIdx.x == 0) npart[blockIdx.x] = tot;
}

// Pair kernel (R13 inner loop, unchanged) + fused finalize via last-block-
// done: each block stores its partial, fences, bumps a device counter; the
// 1296th block re-fences and reduces all partials + norm partials, writing
// the 3 outputs. Saves the finalize dispatch + inter-dispatch gap.
__global__ __launch_bounds__(256)
void pair_kernel(const char* __restrict__ wsb, float* __restrict__ out) {
    __shared__ float smem4[4];
    __shared__ int lastFlag;

    const __fp16* rowfeat = (const __fp16*)(wsb + OFF_ROWFEAT);
    const __fp16* rowgeo  = (const __fp16*)(wsb + OFF_ROWGEO);
    const __fp16* colfeat = (const __fp16*)(wsb + OFF_COLFEAT);
    const __fp16* colB1   = (const __fp16*)(wsb + OFF_COLB1);
    const __fp16* colB2   = (const __fp16*)(wsb + OFF_COLB2);
    float*        part    = (float*)(const_cast<char*>(wsb) + OFF_PART);
    const float*  npart   = (const float*)(wsb + OFF_NPART);
    unsigned int* cnt     = (unsigned int*)(const_cast<char*>(wsb) + OFF_CNT);

    const int t = threadIdx.x;
    const int w = t >> 6;
    const int L = t & 63;
    const int c31 = L & 31;
    const int kh8 = (L >> 5) * 8;

    // A fragments: loaded once, live across the column sweep
    const int arow = blockIdx.y * 128 + w * 32 + c31;
    const v8h afeat = *(const v8h*)(rowfeat + (size_t)arow * 16 + kh8);
    const v8h ageo  = *(const v8h*)(rowgeo  + (size_t)arow * 16 + kh8);

    const int cbase = blockIdx.x * 288;   // 9 tiles * 32 cols
    const size_t boff0 = (size_t)(cbase + c31) * 16 + kh8;

    float acc0 = 0.0f, acc1 = 0.0f;

    // depth-2 pipeline, 3 rotating buffers (fully unrolled -> static indices)
    v8h BF[3], B1[3], B2[3];
    #pragma unroll
    for (int s = 0; s < 2; s++) {
        const size_t o = boff0 + (size_t)s * 32 * 16;
        BF[s] = *(const v8h*)(colfeat + o);
        B1[s] = *(const v8h*)(colB1   + o);
        B2[s] = *(const v8h*)(colB2   + o);
    }

    #pragma unroll
    for (int ct = 0; ct < 9; ct++) {
        const int cur = ct % 3;
        if (ct < 7) {
            const int nxt = (ct + 2) % 3;
            const size_t o = boff0 + (size_t)(ct + 2) * 32 * 16;
            BF[nxt] = *(const v8h*)(colfeat + o);
            B1[nxt] = *(const v8h*)(colB1   + o);
            B2[nxt] = *(const v8h*)(colB2   + o);
        }

        v16f z = {};
        const v16f dotv = __builtin_amdgcn_mfma_f32_32x32x16_f16(afeat, BF[cur], z, 0, 0, 0);
        const v16f a1v  = __builtin_amdgcn_mfma_f32_32x32x16_f16(ageo,  B1[cur], z, 0, 0, 0);
        const v16f a2v  = __builtin_amdgcn_mfma_f32_32x32x16_f16(ageo,  B2[cur], z, 0, 0, 0);

        #pragma unroll
        for (int i = 0; i < 8; i++) {
            const float e1a = fast_exp2(a1v[i]);
            const float e2a = fast_exp2(a2v[i]);
            const float e1b = fast_exp2(a1v[i + 8]);
            const float e2b = fast_exp2(a2v[i + 8]);
            acc0 = fmaf(e1a - e2a, dotv[i], acc0);
            acc1 = fmaf(e1b - e2b, dotv[i + 8], acc1);
        }
    }

    // block reduction -> partial store, then last-block-done detection
    float v = wave_reduce_64(acc0 + acc1);
    if (L == 0) smem4[w] = v;
    __syncthreads();
    if (t == 0) {
        part[blockIdx.y * 24 + blockIdx.x] = smem4[0] + smem4[1] + smem4[2] + smem4[3];
        __threadfence();                         // make partial visible device-wide
        const unsigned int old = atomicAdd(cnt, 1u);
        lastFlag = (old == NPART_BLOCKS - 1) ? 1 : 0;
    }
    __syncthreads();

    if (lastFlag) {
        __threadfence();   // acquire: all partials visible after observing count
        float s = 0.0f;
        for (int i = t; i < NPART_BLOCKS; i += 256) s += part[i];
        const float tot = block_reduce_256(s, smem4);

        float ns = (t < NNORM_BLOCKS) ? npart[t] : 0.0f;
        const float ntot = block_reduce_256(ns, smem4);

        if (t == 0) {
            const float vc = -tot * (1.0f / (float)NPIX);
            out[0] = vc;             // final_loss
            out[1] = vc;             // inner_neg
            out[2] = 100.0f * ntot;  // fea_norm_sum
        }
    }
}

extern "C" void kernel_launch(void* const* d_in, const int* in_sizes, int n_in,
                              void* d_out, int out_size, void* d_ws, size_t ws_size,
                              hipStream_t stream) {
    const float* feature1 = (const float*)d_in[0];
    const float* feature2 = (const float*)d_in[1];
    const float* depth1   = (const float*)d_in[2];
    const float* depth2   = (const float*)d_in[3];
    const float* pose1_2  = (const float*)d_in[4];
    const float* posenz   = (const float*)d_in[5];
    float* out = (float*)d_out;
    char*  wsb = (char*)d_ws;

    preproc_kernel<<<108, 64, 0, stream>>>(feature1, feature2, depth1, depth2,
                                           pose1_2, posenz, wsb);
    dim3 grid(24, 54);
    pair_kernel<<<grid, 256, 0, stream>>>(wsb, out);
}

// Round 16
// 92.003 us; speedup vs baseline: 1.1169x; 1.1169x over previous
//
#include <hip/hip_runtime.h>
#include <math.h>

// Problem constants: FX=FY=48, CX=48, CY=36, H=72, W=96, sigma2=1
#define NPIX 6912
#define LOG2E 1.4426950408889634f

typedef __fp16 v8h  __attribute__((ext_vector_type(8)));
typedef float  v16f __attribute__((ext_vector_type(16)));

// ws byte offsets (32B-aligned). All f16 arrays [N][16] (32 B per pixel).
// A-side (rows, pixel m):
//   rowfeat: k0..15 = f1n features (16)
//   rowgeo : k0..2=ph, k3..5=ph, k6..8=pl, k9=1, k10=1, k11=w_h, k12=w_l, k13..15=0
//            (p~ = log2e*p1 hi/lo split; w = -log2e*|p1|^2/2 hi/lo split)
// B-side (cols, pixel n):
//   colfeat: k0..15 = f2n features
//   colB1  : k0..2=th, k3..5=tl, k6..8=th, k9=cA_h, k10=cA_l, k11=1, k12=1, rest 0
//   colB2  : k0..2=qh, k3..5=ql, k6..8=qh, k9=cB_h, k10=cB_l, k11=1, k12=1, rest 0
// MFMA(ageo,colB1) = p~.t + cA + w = a1;  MFMA(ageo,colB2) = p~.q + cB + w = a2
// loss slot: (2^a1 - 2^a2) * dot.   [R13 numerics, absmax 7.2e-7]
// R16 change: 2^x computed with full-rate VALU (floor + deg-5 poly + ldexp)
// instead of v_exp_f32 — the trans pipe (~64 cyc/wave-exp measured across
// R1..R15) was the 40 µs bottleneck.
#define OFF_ROWFEAT 0
#define OFF_ROWGEO  221184
#define OFF_COLFEAT 442368
#define OFF_COLB1   663552
#define OFF_COLB2   884736
#define OFF_PART    1105920   // [1296] f32 pair-kernel block partials
#define OFF_NPART   1111104   // [108]  f32 preproc norm partials
#define NPART_BLOCKS 1296     // 24 x 54
#define NNORM_BLOCKS 108

// 2^x on the VALU: x = f + r, f=floor(x), r in [0,1).
// 2^r via Taylor deg-5 (rel err ~8e-5), then v_ldexp_f32 by (int)f.
// For x < -126 ldexp flushes to 0 (same as exp underflow). 9 full-rate ops.
__device__ __forceinline__ float poly_exp2(float x) {
    const float f = floorf(x);
    const float r = x - f;
    float p = fmaf(r, 0.0013333558f, 0.0096181291f);   // ln^5(2)/120, ln^4(2)/24
    p = fmaf(r, p, 0.0555041087f);                     // ln^3(2)/6
    p = fmaf(r, p, 0.2402265070f);                     // ln^2(2)/2
    p = fmaf(r, p, 0.6931471806f);                     // ln(2)
    p = fmaf(r, p, 1.0f);
    return ldexpf(p, (int)f);                          // v_ldexp_f32
}

__device__ __forceinline__ float wave_reduce_64(float v) {
    #pragma unroll
    for (int o = 32; o > 0; o >>= 1) v += __shfl_down(v, o, 64);
    return v;
}

__device__ __forceinline__ float block_reduce_256(float v, float* smem4) {
    __syncthreads();   // protect smem4 across consecutive reductions
    v = wave_reduce_64(v);
    const int lane = threadIdx.x & 63;
    const int w = threadIdx.x >> 6;
    if (lane == 0) smem4[w] = v;
    __syncthreads();
    float r = 0.0f;
    if (threadIdx.x == 0) r = smem4[0] + smem4[1] + smem4[2] + smem4[3];
    return r;
}

__device__ __forceinline__ void split_hl(float x, __fp16& h, __fp16& l) {
    h = (__fp16)x;
    l = (__fp16)(x - (float)h);
}

// 108 blocks x 64 threads (one wave per block); no atomics (partial store).
__global__ __launch_bounds__(64)
void preproc_kernel(const float* __restrict__ f1, const float* __restrict__ f2,
                    const float* __restrict__ d1, const float* __restrict__ d2,
                    const float* __restrict__ pose, const float* __restrict__ pnz,
                    char* __restrict__ wsb) {
    const int i = blockIdx.x * 64 + threadIdx.x;

    __fp16* rowfeat = (__fp16*)(wsb + OFF_ROWFEAT);
    __fp16* rowgeo  = (__fp16*)(wsb + OFF_ROWGEO);
    __fp16* colfeat = (__fp16*)(wsb + OFF_COLFEAT);
    __fp16* colB1   = (__fp16*)(wsb + OFF_COLB1);
    __fp16* colB2   = (__fp16*)(wsb + OFF_COLB2);
    float*  npart   = (float*)(wsb + OFF_NPART);

    float P[12];
    #pragma unroll
    for (int k = 0; k < 12; k++) P[k] = pose[k];
    float Q[12];
    #pragma unroll
    for (int r = 0; r < 3; r++) {
        #pragma unroll
        for (int c = 0; c < 4; c++) {
            float s = 0.0f;
            #pragma unroll
            for (int k = 0; k < 4; k++) s = fmaf(pose[r * 4 + k], pnz[k * 4 + c], s);
            Q[r * 4 + c] = s;
        }
    }

    const float inv48 = 1.0f / 48.0f;
    const int u = i % 96;
    const int v = i / 96;
    const float y1 = fmaf((float)u, inv48, -1.0f);
    const float y2 = fmaf((float)v, inv48, -0.75f);

    // ---- row side ----
    const float dep1 = d1[i];
    const float px = dep1, py = y1 * dep1, pz = y2 * dep1;
    const float n1 = px * px + py * py + pz * pz;
    const float wlog = -0.5f * LOG2E * n1;

    const float ptx = LOG2E * px, pty = LOG2E * py, ptz = LOG2E * pz;
    __fp16 phx, phy, phz, plx, ply, plz, wh, wl;
    split_hl(ptx, phx, plx);
    split_hl(pty, phy, ply);
    split_hl(ptz, phz, plz);
    split_hl(wlog, wh, wl);
    {
        __fp16 rg[16] = {phx, phy, phz,  phx, phy, phz,  plx, ply, plz,
                         (__fp16)1.0f, (__fp16)1.0f, wh, wl,
                         (__fp16)0, (__fp16)0, (__fp16)0};
        *(v8h*)(rowgeo + (size_t)i * 16)     = *(v8h*)(rg);
        *(v8h*)(rowgeo + (size_t)i * 16 + 8) = *(v8h*)(rg + 8);
    }

    // ---- col side ----
    const float dep2 = d2[i];
    const float a = dep2, b = y1 * dep2, g = y2 * dep2;
    const float t0 = P[0] * a + P[1] * b + P[2]  * g + P[3];
    const float t1 = P[4] * a + P[5] * b + P[6]  * g + P[7];
    const float t2 = P[8] * a + P[9] * b + P[10] * g + P[11];
    const float q0 = Q[0] * a + Q[1] * b + Q[2]  * g + Q[3];
    const float q1 = Q[4] * a + Q[5] * b + Q[6]  * g + Q[7];
    const float q2 = Q[8] * a + Q[9] * b + Q[10] * g + Q[11];
    const float nt = t0 * t0 + t1 * t1 + t2 * t2;
    const float nq = q0 * q0 + q1 * q1 + q2 * q2;
    const float cA = -0.5f * LOG2E * nt;
    const float cB = -0.5f * LOG2E * nq;

    __fp16 thx, thy, thz, tlx, tly, tlz, cAh, cAl;
    __fp16 qhx, qhy, qhz, qlx, qly, qlz, cBh, cBl;
    split_hl(t0, thx, tlx);
    split_hl(t1, thy, tly);
    split_hl(t2, thz, tlz);
    split_hl(cA, cAh, cAl);
    split_hl(q0, qhx, qlx);
    split_hl(q1, qhy, qly);
    split_hl(q2, qhz, qlz);
    split_hl(cB, cBh, cBl);
    {
        __fp16 b1a[16] = {thx, thy, thz,  tlx, tly, tlz,  thx, thy, thz,
                          cAh, cAl, (__fp16)1.0f, (__fp16)1.0f,
                          (__fp16)0, (__fp16)0, (__fp16)0};
        *(v8h*)(colB1 + (size_t)i * 16)     = *(v8h*)(b1a);
        *(v8h*)(colB1 + (size_t)i * 16 + 8) = *(v8h*)(b1a + 8);
    }
    {
        __fp16 b2a[16] = {qhx, qhy, qhz,  qlx, qly, qlz,  qhx, qhy, qhz,
                          cBh, cBl, (__fp16)1.0f, (__fp16)1.0f,
                          (__fp16)0, (__fp16)0, (__fp16)0};
        *(v8h*)(colB2 + (size_t)i * 16)     = *(v8h*)(b2a);
        *(v8h*)(colB2 + (size_t)i * 16 + 8) = *(v8h*)(b2a + 8);
    }

    // ---- features: normalize, f16 ----
    float s1 = 0.0f, s2 = 0.0f;
    float v1[16], v2[16];
    #pragma unroll
    for (int cc = 0; cc < 16; cc++) {
        v1[cc] = f1[cc * NPIX + i];
        v2[cc] = f2[cc * NPIX + i];
        s1 = fmaf(v1[cc], v1[cc], s1);
        s2 = fmaf(v2[cc], v2[cc], s2);
    }
    const float nrm1 = sqrtf(s1), nrm2 = sqrtf(s2);
    const float r1 = 1.0f / (nrm1 + 1e-8f), r2 = 1.0f / (nrm2 + 1e-8f);
    {
        __fp16 rf[16], cf[16];
        #pragma unroll
        for (int cc = 0; cc < 16; cc++) {
            rf[cc] = (__fp16)(v1[cc] * r1);
            cf[cc] = (__fp16)(v2[cc] * r2);
        }
        *(v8h*)(rowfeat + (size_t)i * 16)     = *(v8h*)(rf);
        *(v8h*)(rowfeat + (size_t)i * 16 + 8) = *(v8h*)(rf + 8);
        *(v8h*)(colfeat + (size_t)i * 16)     = *(v8h*)(cf);
        *(v8h*)(colfeat + (size_t)i * 16 + 8) = *(v8h*)(cf + 8);
    }

    float tot = wave_reduce_64(nrm1 + nrm2);
    if (threadIdx.x == 0) npart[blockIdx.x] = tot;
}

// Pair kernel: grid (24, 54), block = 4 waves (R13 structure). No LDS, no
// atomics. Each wave owns ONE 32-row MFMA row-group, sweeps 9 col-tiles of
// 32 columns, depth-2 prefetch, dual accumulators. Epilogue exps now on the
// full-rate VALU (poly_exp2) instead of the slow trans pipe.
__global__ __launch_bounds__(256)
void pair_kernel(const char* __restrict__ wsb) {
    __shared__ float smem4[4];

    const __fp16* rowfeat = (const __fp16*)(wsb + OFF_ROWFEAT);
    const __fp16* rowgeo  = (const __fp16*)(wsb + OFF_ROWGEO);
    const __fp16* colfeat = (const __fp16*)(wsb + OFF_COLFEAT);
    const __fp16* colB1   = (const __fp16*)(wsb + OFF_COLB1);
    const __fp16* colB2   = (const __fp16*)(wsb + OFF_COLB2);
    float*        part    = (float*)(const_cast<char*>(wsb) + OFF_PART);

    const int t = threadIdx.x;
    const int w = t >> 6;
    const int L = t & 63;
    const int c31 = L & 31;
    const int kh8 = (L >> 5) * 8;

    // A fragments: loaded once, live across the column sweep
    const int arow = blockIdx.y * 128 + w * 32 + c31;
    const v8h afeat = *(const v8h*)(rowfeat + (size_t)arow * 16 + kh8);
    const v8h ageo  = *(const v8h*)(rowgeo  + (size_t)arow * 16 + kh8);

    const int cbase = blockIdx.x * 288;   // 9 tiles * 32 cols
    const size_t boff0 = (size_t)(cbase + c31) * 16 + kh8;

    float acc0 = 0.0f, acc1 = 0.0f;

    // depth-2 pipeline, 3 rotating buffers (fully unrolled -> static indices)
    v8h BF[3], B1[3], B2[3];
    #pragma unroll
    for (int s = 0; s < 2; s++) {
        const size_t o = boff0 + (size_t)s * 32 * 16;
        BF[s] = *(const v8h*)(colfeat + o);
        B1[s] = *(const v8h*)(colB1   + o);
        B2[s] = *(const v8h*)(colB2   + o);
    }

    #pragma unroll
    for (int ct = 0; ct < 9; ct++) {
        const int cur = ct % 3;
        if (ct < 7) {
            const int nxt = (ct + 2) % 3;
            const size_t o = boff0 + (size_t)(ct + 2) * 32 * 16;
            BF[nxt] = *(const v8h*)(colfeat + o);
            B1[nxt] = *(const v8h*)(colB1   + o);
            B2[nxt] = *(const v8h*)(colB2   + o);
        }

        v16f z = {};
        const v16f dotv = __builtin_amdgcn_mfma_f32_32x32x16_f16(afeat, BF[cur], z, 0, 0, 0);
        const v16f a1v  = __builtin_amdgcn_mfma_f32_32x32x16_f16(ageo,  B1[cur], z, 0, 0, 0);
        const v16f a2v  = __builtin_amdgcn_mfma_f32_32x32x16_f16(ageo,  B2[cur], z, 0, 0, 0);

        #pragma unroll
        for (int i = 0; i < 8; i++) {
            const float e1a = poly_exp2(a1v[i]);
            const float e2a = poly_exp2(a2v[i]);
            const float e1b = poly_exp2(a1v[i + 8]);
            const float e2b = poly_exp2(a2v[i + 8]);
            acc0 = fmaf(e1a - e2a, dotv[i], acc0);
            acc1 = fmaf(e1b - e2b, dotv[i + 8], acc1);
        }
    }

    // block reduction -> one plain store per block (no atomics)
    float v = wave_reduce_64(acc0 + acc1);
    if (L == 0) smem4[w] = v;
    __syncthreads();
    if (t == 0)
        part[blockIdx.y * 24 + blockIdx.x] = smem4[0] + smem4[1] + smem4[2] + smem4[3];
}

// Single-block finalize: reduce 1296 pair partials + 108 norm partials,
// write all 3 outputs directly.
__global__ __launch_bounds__(256)
void finalize_kernel(const char* __restrict__ wsb, float* __restrict__ out) {
    __shared__ float smem4[4];
    const float* part  = (const float*)(wsb + OFF_PART);
    const float* npart = (const float*)(wsb + OFF_NPART);
    const int t = threadIdx.x;

    float s = 0.0f;
    for (int i = t; i < NPART_BLOCKS; i += 256) s += part[i];
    const float tot = block_reduce_256(s, smem4);

    float ns = (t < NNORM_BLOCKS) ? npart[t] : 0.0f;
    const float ntot = block_reduce_256(ns, smem4);

    if (t == 0) {
        const float vc = -tot * (1.0f / (float)NPIX);
        out[0] = vc;             // final_loss
        out[1] = vc;             // inner_neg
        out[2] = 100.0f * ntot;  // fea_norm_sum
    }
}

extern "C" void kernel_launch(void* const* d_in, const int* in_sizes, int n_in,
                              void* d_out, int out_size, void* d_ws, size_t ws_size,
                              hipStream_t stream) {
    const float* feature1 = (const float*)d_in[0];
    const float* feature2 = (const float*)d_in[1];
    const float* depth1   = (const float*)d_in[2];
    const float* depth2   = (const float*)d_in[3];
    const float* pose1_2  = (const float*)d_in[4];
    const float* posenz   = (const float*)d_in[5];
    float* out = (float*)d_out;
    char*  wsb = (char*)d_ws;

    preproc_kernel<<<108, 64, 0, stream>>>(feature1, feature2, depth1, depth2,
                                           pose1_2, posenz, wsb);
    dim3 grid(24, 54);
    pair_kernel<<<grid, 256, 0, stream>>>(wsb);
    finalize_kernel<<<1, 256, 0, stream>>>(wsb, out);
}

// Round 17
// 85.307 us; speedup vs baseline: 1.2046x; 1.0785x over previous
//
#include <hip/hip_runtime.h>
#include <math.h>

// Problem constants: FX=FY=48, CX=48, CY=36, H=72, W=96, sigma2=1
#define NPIX 6912
#define LOG2E 1.4426950408889634f

typedef __fp16 v8h  __attribute__((ext_vector_type(8)));
typedef float  v16f __attribute__((ext_vector_type(16)));

// ws byte offsets (32B-aligned). All f16 arrays [N][16] (32 B per pixel).
// A-side (rows, pixel m):
//   rowfeat: k0..15 = f1n features (16)
//   rowgeo : k0..2=ph, k3..5=ph, k6..8=pl, k9=1, k10=1, k11=w_h, k12=w_l, k13..15=0
//            (p~ = log2e*p1 hi/lo split; w = -log2e*|p1|^2/2 hi/lo split)
// B-side (cols, pixel n):
//   colfeat: k0..15 = f2n features
//   colB1  : k0..2=th, k3..5=tl, k6..8=th, k9=cA_h, k10=cA_l, k11=1, k12=1, rest 0
//   colB2  : k0..2=qh, k3..5=ql, k6..8=qh, k9=cB_h, k10=cB_l, k11=1, k12=1, rest 0
// MFMA(ageo,colB1) = p~.t + cA + w = a1;  MFMA(ageo,colB2) = p~.q + cB + w = a2
// loss slot: (2^a1 - 2^a2) * dot.   [R13 numerics, absmax 7.2e-7]
// R17 change: ROLLED tile loop (#pragma unroll 1) + depth-1 prefetch in named
// regs. The unrolled 9-tile body with 3 rotating buffer triples needed ~100+
// live VGPRs against an 80-VGPR allocation (R15 counters: 269 VALU/tile-visit
// vs ~130 static -> rematerialization/spill), and ~19 KB of straight-line
// code. Small body = lower pressure + compiler software-pipelining.
#define OFF_ROWFEAT 0
#define OFF_ROWGEO  221184
#define OFF_COLFEAT 442368
#define OFF_COLB1   663552
#define OFF_COLB2   884736
#define OFF_PART    1105920   // [1296] f32 pair-kernel block partials
#define OFF_NPART   1111104   // [108]  f32 preproc norm partials
#define NPART_BLOCKS 1296     // 24 x 54
#define NNORM_BLOCKS 108

__device__ __forceinline__ float fast_exp2(float x) { return __builtin_amdgcn_exp2f(x); }

__device__ __forceinline__ float wave_reduce_64(float v) {
    #pragma unroll
    for (int o = 32; o > 0; o >>= 1) v += __shfl_down(v, o, 64);
    return v;
}

__device__ __forceinline__ float block_reduce_256(float v, float* smem4) {
    __syncthreads();   // protect smem4 across consecutive reductions
    v = wave_reduce_64(v);
    const int lane = threadIdx.x & 63;
    const int w = threadIdx.x >> 6;
    if (lane == 0) smem4[w] = v;
    __syncthreads();
    float r = 0.0f;
    if (threadIdx.x == 0) r = smem4[0] + smem4[1] + smem4[2] + smem4[3];
    return r;
}

__device__ __forceinline__ void split_hl(float x, __fp16& h, __fp16& l) {
    h = (__fp16)x;
    l = (__fp16)(x - (float)h);
}

// 108 blocks x 64 threads (one wave per block); no atomics (partial store).
__global__ __launch_bounds__(64)
void preproc_kernel(const float* __restrict__ f1, const float* __restrict__ f2,
                    const float* __restrict__ d1, const float* __restrict__ d2,
                    const float* __restrict__ pose, const float* __restrict__ pnz,
                    char* __restrict__ wsb) {
    const int i = blockIdx.x * 64 + threadIdx.x;

    __fp16* rowfeat = (__fp16*)(wsb + OFF_ROWFEAT);
    __fp16* rowgeo  = (__fp16*)(wsb + OFF_ROWGEO);
    __fp16* colfeat = (__fp16*)(wsb + OFF_COLFEAT);
    __fp16* colB1   = (__fp16*)(wsb + OFF_COLB1);
    __fp16* colB2   = (__fp16*)(wsb + OFF_COLB2);
    float*  npart   = (float*)(wsb + OFF_NPART);

    float P[12];
    #pragma unroll
    for (int k = 0; k < 12; k++) P[k] = pose[k];
    float Q[12];
    #pragma unroll
    for (int r = 0; r < 3; r++) {
        #pragma unroll
        for (int c = 0; c < 4; c++) {
            float s = 0.0f;
            #pragma unroll
            for (int k = 0; k < 4; k++) s = fmaf(pose[r * 4 + k], pnz[k * 4 + c], s);
            Q[r * 4 + c] = s;
        }
    }

    const float inv48 = 1.0f / 48.0f;
    const int u = i % 96;
    const int v = i / 96;
    const float y1 = fmaf((float)u, inv48, -1.0f);
    const float y2 = fmaf((float)v, inv48, -0.75f);

    // ---- row side ----
    const float dep1 = d1[i];
    const float px = dep1, py = y1 * dep1, pz = y2 * dep1;
    const float n1 = px * px + py * py + pz * pz;
    const float wlog = -0.5f * LOG2E * n1;

    const float ptx = LOG2E * px, pty = LOG2E * py, ptz = LOG2E * pz;
    __fp16 phx, phy, phz, plx, ply, plz, wh, wl;
    split_hl(ptx, phx, plx);
    split_hl(pty, phy, ply);
    split_hl(ptz, phz, plz);
    split_hl(wlog, wh, wl);
    {
        __fp16 rg[16] = {phx, phy, phz,  phx, phy, phz,  plx, ply, plz,
                         (__fp16)1.0f, (__fp16)1.0f, wh, wl,
                         (__fp16)0, (__fp16)0, (__fp16)0};
        *(v8h*)(rowgeo + (size_t)i * 16)     = *(v8h*)(rg);
        *(v8h*)(rowgeo + (size_t)i * 16 + 8) = *(v8h*)(rg + 8);
    }

    // ---- col side ----
    const float dep2 = d2[i];
    const float a = dep2, b = y1 * dep2, g = y2 * dep2;
    const float t0 = P[0] * a + P[1] * b + P[2]  * g + P[3];
    const float t1 = P[4] * a + P[5] * b + P[6]  * g + P[7];
    const float t2 = P[8] * a + P[9] * b + P[10] * g + P[11];
    const float q0 = Q[0] * a + Q[1] * b + Q[2]  * g + Q[3];
    const float q1 = Q[4] * a + Q[5] * b + Q[6]  * g + Q[7];
    const float q2 = Q[8] * a + Q[9] * b + Q[10] * g + Q[11];
    const float nt = t0 * t0 + t1 * t1 + t2 * t2;
    const float nq = q0 * q0 + q1 * q1 + q2 * q2;
    const float cA = -0.5f * LOG2E * nt;
    const float cB = -0.5f * LOG2E * nq;

    __fp16 thx, thy, thz, tlx, tly, tlz, cAh, cAl;
    __fp16 qhx, qhy, qhz, qlx, qly, qlz, cBh, cBl;
    split_hl(t0, thx, tlx);
    split_hl(t1, thy, tly);
    split_hl(t2, thz, tlz);
    split_hl(cA, cAh, cAl);
    split_hl(q0, qhx, qlx);
    split_hl(q1, qhy, qly);
    split_hl(q2, qhz, qlz);
    split_hl(cB, cBh, cBl);
    {
        __fp16 b1a[16] = {thx, thy, thz,  tlx, tly, tlz,  thx, thy, thz,
                          cAh, cAl, (__fp16)1.0f, (__fp16)1.0f,
                          (__fp16)0, (__fp16)0, (__fp16)0};
        *(v8h*)(colB1 + (size_t)i * 16)     = *(v8h*)(b1a);
        *(v8h*)(colB1 + (size_t)i * 16 + 8) = *(v8h*)(b1a + 8);
    }
    {
        __fp16 b2a[16] = {qhx, qhy, qhz,  qlx, qly, qlz,  qhx, qhy, qhz,
                          cBh, cBl, (__fp16)1.0f, (__fp16)1.0f,
                          (__fp16)0, (__fp16)0, (__fp16)0};
        *(v8h*)(colB2 + (size_t)i * 16)     = *(v8h*)(b2a);
        *(v8h*)(colB2 + (size_t)i * 16 + 8) = *(v8h*)(b2a + 8);
    }

    // ---- features: normalize, f16 ----
    float s1 = 0.0f, s2 = 0.0f;
    float v1[16], v2[16];
    #pragma unroll
    for (int cc = 0; cc < 16; cc++) {
        v1[cc] = f1[cc * NPIX + i];
        v2[cc] = f2[cc * NPIX + i];
        s1 = fmaf(v1[cc], v1[cc], s1);
        s2 = fmaf(v2[cc], v2[cc], s2);
    }
    const float nrm1 = sqrtf(s1), nrm2 = sqrtf(s2);
    const float r1 = 1.0f / (nrm1 + 1e-8f), r2 = 1.0f / (nrm2 + 1e-8f);
    {
        __fp16 rf[16], cf[16];
        #pragma unroll
        for (int cc = 0; cc < 16; cc++) {
            rf[cc] = (__fp16)(v1[cc] * r1);
            cf[cc] = (__fp16)(v2[cc] * r2);
        }
        *(v8h*)(rowfeat + (size_t)i * 16)     = *(v8h*)(rf);
        *(v8h*)(rowfeat + (size_t)i * 16 + 8) = *(v8h*)(rf + 8);
        *(v8h*)(colfeat + (size_t)i * 16)     = *(v8h*)(cf);
        *(v8h*)(colfeat + (size_t)i * 16 + 8) = *(v8h*)(cf + 8);
    }

    float tot = wave_reduce_64(nrm1 + nrm2);
    if (threadIdx.x == 0) npart[blockIdx.x] = tot;
}

// One tile of work: 3 MFMAs + exp epilogue (dual accumulators).
__device__ __forceinline__ void tile_body(const v8h& afeat, const v8h& ageo,
                                          const v8h& bf, const v8h& b1, const v8h& b2,
                                          float& acc0, float& acc1) {
    v16f z = {};
    const v16f dotv = __builtin_amdgcn_mfma_f32_32x32x16_f16(afeat, bf, z, 0, 0, 0);
    const v16f a1v  = __builtin_amdgcn_mfma_f32_32x32x16_f16(ageo,  b1, z, 0, 0, 0);
    const v16f a2v  = __builtin_amdgcn_mfma_f32_32x32x16_f16(ageo,  b2, z, 0, 0, 0);
    #pragma unroll
    for (int i = 0; i < 8; i++) {
        const float e1a = fast_exp2(a1v[i]);
        const float e2a = fast_exp2(a2v[i]);
        const float e1b = fast_exp2(a1v[i + 8]);
        const float e2b = fast_exp2(a2v[i + 8]);
        acc0 = fmaf(e1a - e2a, dotv[i], acc0);
        acc1 = fmaf(e1b - e2b, dotv[i + 8], acc1);
    }
}

// Pair kernel: grid (24, 54), block = 4 waves. No LDS in hot path, no
// atomics. Each wave owns ONE 32-row MFMA row-group, sweeps 9 col-tiles of
// 32 columns. ROLLED loop (small body, low VGPR pressure), depth-1 prefetch
// in named registers, tail tile outside the loop.
__global__ __launch_bounds__(256)
void pair_kernel(const char* __restrict__ wsb) {
    __shared__ float smem4[4];

    const __fp16* rowfeat = (const __fp16*)(wsb + OFF_ROWFEAT);
    const __fp16* rowgeo  = (const __fp16*)(wsb + OFF_ROWGEO);
    const __fp16* colfeat = (const __fp16*)(wsb + OFF_COLFEAT);
    const __fp16* colB1   = (const __fp16*)(wsb + OFF_COLB1);
    const __fp16* colB2   = (const __fp16*)(wsb + OFF_COLB2);
    float*        part    = (float*)(const_cast<char*>(wsb) + OFF_PART);

    const int t = threadIdx.x;
    const int w = t >> 6;
    const int L = t & 63;
    const int c31 = L & 31;
    const int kh8 = (L >> 5) * 8;

    // A fragments: loaded once, live across the column sweep
    const int arow = blockIdx.y * 128 + w * 32 + c31;
    const v8h afeat = *(const v8h*)(rowfeat + (size_t)arow * 16 + kh8);
    const v8h ageo  = *(const v8h*)(rowgeo  + (size_t)arow * 16 + kh8);

    const int cbase = blockIdx.x * 288;   // 9 tiles * 32 cols
    const size_t boff0 = (size_t)(cbase + c31) * 16 + kh8;

    float acc0 = 0.0f, acc1 = 0.0f;

    v8h bf = *(const v8h*)(colfeat + boff0);
    v8h b1 = *(const v8h*)(colB1   + boff0);
    v8h b2 = *(const v8h*)(colB2   + boff0);

    #pragma unroll 1
    for (int ct = 0; ct < 8; ct++) {
        const size_t o = boff0 + (size_t)(ct + 1) * 32 * 16;
        const v8h nbf = *(const v8h*)(colfeat + o);
        const v8h nb1 = *(const v8h*)(colB1   + o);
        const v8h nb2 = *(const v8h*)(colB2   + o);

        tile_body(afeat, ageo, bf, b1, b2, acc0, acc1);

        bf = nbf; b1 = nb1; b2 = nb2;
    }
    // tail tile
    tile_body(afeat, ageo, bf, b1, b2, acc0, acc1);

    // block reduction -> one plain store per block (no atomics)
    float v = wave_reduce_64(acc0 + acc1);
    if (L == 0) smem4[w] = v;
    __syncthreads();
    if (t == 0)
        part[blockIdx.y * 24 + blockIdx.x] = smem4[0] + smem4[1] + smem4[2] + smem4[3];
}

// Single-block finalize: reduce 1296 pair partials + 108 norm partials,
// write all 3 outputs directly.
__global__ __launch_bounds__(256)
void finalize_kernel(const char* __restrict__ wsb, float* __restrict__ out) {
    __shared__ float smem4[4];
    const float* part  = (const float*)(wsb + OFF_PART);
    const float* npart = (const float*)(wsb + OFF_NPART);
    const int t = threadIdx.x;

    float s = 0.0f;
    for (int i = t; i < NPART_BLOCKS; i += 256) s += part[i];
    const float tot = block_reduce_256(s, smem4);

    float ns = (t < NNORM_BLOCKS) ? npart[t] : 0.0f;
    const float ntot = block_reduce_256(ns, smem4);

    if (t == 0) {
        const float vc = -tot * (1.0f / (float)NPIX);
        out[0] = vc;             // final_loss
        out[1] = vc;             // inner_neg
        out[2] = 100.0f * ntot;  // fea_norm_sum
    }
}

extern "C" void kernel_launch(void* const* d_in, const int* in_sizes, int n_in,
                              void* d_out, int out_size, void* d_ws, size_t ws_size,
                              hipStream_t stream) {
    const float* feature1 = (const float*)d_in[0];
    const float* feature2 = (const float*)d_in[1];
    const float* depth1   = (const float*)d_in[2];
    const float* depth2   = (const float*)d_in[3];
    const float* pose1_2  = (const float*)d_in[4];
    const float* posenz   = (const float*)d_in[5];
    float* out = (float*)d_out;
    char*  wsb = (char*)d_ws;

    preproc_kernel<<<108, 64, 0, stream>>>(feature1, feature2, depth1, depth2,
                                           pose1_2, posenz, wsb);
    dim3 grid(24, 54);
    pair_kernel<<<grid, 256, 0, stream>>>(wsb);
    finalize_kernel<<<1, 256, 0, stream>>>(wsb, out);
}